// Round 2
// baseline (2303.252 us; speedup 1.0000x reference)
//
#include <hip/hip_runtime.h>
#include <hip/hip_bf16.h>
#include <math.h>
#include <stdint.h>

#define BB 32
#define TT 512
#define II 512
#define HH 512
#define G4 (4 * HH)      // 2048
#define MM (TT * BB)     // 16384 rows of gx per direction
#define BH (BB * HH)     // 16384
#define WGD 16           // workgroups per direction in rec kernel (8 waves each)

typedef __hip_bfloat16 bf16;
typedef __attribute__((ext_vector_type(8))) short short8;   // 8 bf16 = 4 VGPRs
typedef __attribute__((ext_vector_type(4))) float f32x4;    // MFMA accumulator
typedef __attribute__((ext_vector_type(4))) unsigned u32x4; // for asm loads

__device__ __forceinline__ float bf2f(bf16 v) { return __bfloat162float(v); }
__device__ __forceinline__ bf16  f2bf(float v) { return __float2bfloat16(v); }
__device__ __forceinline__ short f2bs(float x) { bf16 v = f2bf(x); return *reinterpret_cast<short*>(&v); }
__device__ __forceinline__ float bs2f(short s) {
    unsigned u = ((unsigned)(unsigned short)s) << 16;
    return __uint_as_float(u);
}
__device__ __forceinline__ short8 pk8(float4 u, float4 v) {
    short8 t;
    t[0] = f2bs(u.x); t[1] = f2bs(u.y); t[2] = f2bs(u.z); t[3] = f2bs(u.w);
    t[4] = f2bs(v.x); t[5] = f2bs(v.y); t[6] = f2bs(v.z); t[7] = f2bs(v.w);
    return t;
}

// gx gate-planar swizzle: [dl][t][g][cg 0..127][b*4 + jj] bf16
#define GX1 ((size_t)TT * 4 * 128 * 128)   // elements per direction (= MM*G4)

// ---------------------------------------------------------------------------
// Phase 1: input projection GEMM via MFMA (bf16 in / fp32 acc). Unchanged.
// ---------------------------------------------------------------------------
__global__ __launch_bounds__(256) void proj_mfma_kernel(
    const float* __restrict__ x,
    const float* __restrict__ w_f, const float* __restrict__ w_r,
    const float* __restrict__ bi_f, const float* __restrict__ bh_f,
    const float* __restrict__ bi_r, const float* __restrict__ bh_r,
    bf16* __restrict__ gx, int dir0)
{
    const int dl = blockIdx.z, dir = dir0 + dl;
    const int m0 = blockIdx.x * 64;
    const int n0 = blockIdx.y * 128;
    const float* __restrict__ w  = dir ? w_r  : w_f;
    const float* __restrict__ bi = dir ? bi_r : bi_f;
    const float* __restrict__ bh = dir ? bh_r : bh_f;

    __shared__ __align__(16) char smem[17408];
    bf16 (*As)[40]  = (bf16(*)[40])smem;            // 64 x (32+8 pad)
    bf16 (*Bs)[40]  = (bf16(*)[40])(smem + 5120);   // 128 x (32+8 pad)
    bf16 (*Cs)[136] = (bf16(*)[136])smem;           // 64 x 136 (reuses smem)

    const int tid = threadIdx.x;
    const int wv = tid >> 6, l = tid & 63;
    const int nl = l & 15, ko = (l >> 4) * 8;

    const int a_r = tid >> 2, a_s = tid & 3;
    const float* a_src = x + ((size_t)((m0 + a_r) & 31) * TT + (size_t)((m0 + a_r) >> 5)) * II + a_s * 8;
    const int b_r = tid >> 1, b_h = tid & 1;
    const float* b_src = w + (size_t)(n0 + b_r) * II + b_h * 16;

    f32x4 acc[8];
#pragma unroll
    for (int j = 0; j < 8; ++j) acc[j] = (f32x4){0.f, 0.f, 0.f, 0.f};

    float bias[8];
#pragma unroll
    for (int j = 0; j < 8; ++j) {
        const int n = n0 + j * 16 + nl;
        bias[j] = bi[n] + bh[n];
    }

    for (int k0 = 0; k0 < II; k0 += 32) {
        const float4 av0 = *(const float4*)(a_src + k0);
        const float4 av1 = *(const float4*)(a_src + k0 + 4);
        const float4 bv0 = *(const float4*)(b_src + k0);
        const float4 bv1 = *(const float4*)(b_src + k0 + 4);
        const float4 bv2 = *(const float4*)(b_src + k0 + 8);
        const float4 bv3 = *(const float4*)(b_src + k0 + 12);
        __syncthreads();   // previous tile fully consumed
        *(short8*)&As[a_r][a_s * 8] = pk8(av0, av1);
        *(short8*)&Bs[b_r][b_h * 16]     = pk8(bv0, bv1);
        *(short8*)&Bs[b_r][b_h * 16 + 8] = pk8(bv2, bv3);
        __syncthreads();
        const short8 a = *(const short8*)&As[wv * 16 + nl][ko];
#pragma unroll
        for (int j = 0; j < 8; ++j) {
            const short8 b = *(const short8*)&Bs[j * 16 + nl][ko];
            acc[j] = __builtin_amdgcn_mfma_f32_16x16x32_bf16(a, b, acc[j], 0, 0, 0);
        }
    }

    __syncthreads();
    const int row0 = (l >> 4) * 4;
#pragma unroll
    for (int j = 0; j < 8; ++j)
#pragma unroll
        for (int r = 0; r < 4; ++r)
            Cs[wv * 16 + row0 + r][j * 16 + nl] = f2bf(acc[j][r] + bias[j]);
    __syncthreads();

    bf16* gxd = gx + (size_t)dl * GX1;
    const int g   = n0 >> 9;
    const int cgb = (n0 & 511) >> 2;
    const int t_base = blockIdx.x * 2;
#pragma unroll
    for (int i = 0; i < 4; ++i) {
        const int c = i * 256 + tid;
        const int tl = c >> 9, cgl = (c >> 4) & 31, u = c & 15;
        const int r0 = tl * 32 + 2 * u;
        const uint2 lo = *(const uint2*)&Cs[r0][cgl * 4];
        const uint2 hi = *(const uint2*)&Cs[r0 + 1][cgl * 4];
        uint4 ov; ov.x = lo.x; ov.y = lo.y; ov.z = hi.x; ov.w = hi.y;
        *(uint4*)(gxd + ((((size_t)(t_base + tl) * 4 + g) * 128 + cgb + cgl) * 128 + u * 8)) = ov;
    }
}

// ---------------------------------------------------------------------------
// Phase 2: MFMA recurrence. Round-7 changes:
//  - 16 WGs/dir x 8 waves (512 thr) instead of 32 x 4: half the barrier width,
//    half the restage L3 traffic, per-wave structure unchanged.
//  - barrier arrival = per-WG padded flag STORE (monotonic step count, 128 B
//    stride) instead of 8-way serialized same-address atomic RMW.
//  - every wave polls all 16 flags in parallel (lanes 0..15) and proceeds to
//    its restage independently; post-restage __syncthreads re-converges.
// ---------------------------------------------------------------------------
__global__ __launch_bounds__(512, 2) void lstm_rec_kernel(
    const bf16* __restrict__ gx,
    const float* __restrict__ h0, const float* __restrict__ c0,
    const float* __restrict__ whh_f, const float* __restrict__ whh_r,
    float* __restrict__ dout,
    bf16* __restrict__ h_buf,          // [ndir][2 slots][BH]
    unsigned int* __restrict__ bars,   // [ndir][16 WG flags x 32 uints (128B)]
    int dir0)
{
    const int dl  = blockIdx.x >> 4;
    const int wgl = blockIdx.x & 15;
    const int dir = dir0 + dl;
    const int tid = threadIdx.x;
    const int wv  = tid >> 6;            // wave 0..7
    const int l   = tid & 63;            // lane
    const int cg  = wgl * 8 + wv;        // col-group 0..127
    const int j0  = cg * 4;
    const float* __restrict__ whh = dir ? whh_r : whh_f;
    unsigned int* barsd = bars + (size_t)dl * 512;

    __shared__ __align__(16) bf16 h_s[32][520];   // staged h, +8 pad
    __shared__ __align__(16) float ex[8][16][36]; // per-wave gate exchange

    const int nl = l & 15;                // packed col index = gate*4 + jj
    const int g  = nl >> 2, jj = nl & 3;
    const int ko = (l >> 4) * 8;          // k-octet within a K=32 MFMA step

    // ---- B fragments (w_hh) resident in registers ----
    short8 bfrag[16];
    {
        const float* wr = whh + ((size_t)g * HH + (size_t)(j0 + jj)) * HH;
#pragma unroll
        for (int ks = 0; ks < 16; ++ks) {
            const float* p = wr + ks * 32 + ko;
            short8 t;
#pragma unroll
            for (int i = 0; i < 8; ++i) t[i] = f2bs(p[i]);
            bfrag[ks] = t;
        }
    }

    const int mC = l >> 1;
    const int jjA = (l & 1) * 2;

    float cs0, cs1;
    {
        const float* cp = c0 + (size_t)dir * BH + (size_t)mC * HH + j0 + jjA;
        cs0 = cp[0]; cs1 = cp[1];
    }

    bf16* hsl = h_buf + (size_t)dl * 2 * BH;
    const unsigned* gxw = (const unsigned*)(gx + (size_t)dl * GX1);

    // ---- stage initial h (fp32 h0 -> bf16 LDS) ----
    for (int q = 0; q < 32; ++q) {
        const int f = q * 512 + tid;
        h_s[f >> 9][f & 511] = f2bf(h0[(size_t)dir * BH + f]);
    }
    __syncthreads();

    // first gx fetch: 4 gate-planar dwords (2 cells each)
    unsigned gw[4];
    {
        const int t0 = dir ? (TT - 1) : 0;
#pragma unroll
        for (int gg = 0; gg < 4; ++gg)
            gw[gg] = gxw[((size_t)(t0 * 4 + gg) * 128 + cg) * 64 + l];
    }

#pragma unroll 1
    for (int s = 0; s < TT; ++s) {
        const int t_x = dir ? (TT - 1 - s) : s;

        // ---- MFMA: gates[32 x 16packed] = h . W^T, A from LDS ----
        f32x4 acc0 = {0.f, 0.f, 0.f, 0.f};
        f32x4 acc1 = {0.f, 0.f, 0.f, 0.f};
#pragma unroll
        for (int half = 0; half < 2; ++half) {
            short8 a0[8], a1[8];
#pragma unroll
            for (int k = 0; k < 8; ++k) {
                const int ks = half * 8 + k;
                a0[k] = *(const short8*)&h_s[nl][ks * 32 + ko];
                a1[k] = *(const short8*)&h_s[nl + 16][ks * 32 + ko];
            }
#pragma unroll
            for (int k = 0; k < 8; ++k) {
                acc0 = __builtin_amdgcn_mfma_f32_16x16x32_bf16(a0[k], bfrag[half * 8 + k], acc0, 0, 0, 0);
                acc1 = __builtin_amdgcn_mfma_f32_16x16x32_bf16(a1[k], bfrag[half * 8 + k], acc1, 0, 0, 0);
            }
        }

        // ---- exchange C-layout -> cell layout through per-wave LDS slice ----
        {
            const int row0 = (l >> 4) * 4;
            *(f32x4*)&ex[wv][nl][row0]      = acc0;
            *(f32x4*)&ex[wv][nl][16 + row0] = acc1;
        }

        float hv0, hv1;
#pragma unroll
        for (int c = 0; c < 2; ++c) {
            const int jc = jjA + c;
            const int sh = 16 * c;
            float q0 = ex[wv][0 * 4 + jc][mC] + bs2f((short)(gw[0] >> sh));
            float q1 = ex[wv][1 * 4 + jc][mC] + bs2f((short)(gw[1] >> sh));
            float q2 = ex[wv][2 * 4 + jc][mC] + bs2f((short)(gw[2] >> sh));
            float q3 = ex[wv][3 * 4 + jc][mC] + bs2f((short)(gw[3] >> sh));
            q0 = fminf(fmaxf(q0, -30.f), 30.f);
            q1 = fminf(fmaxf(q1, -30.f), 30.f);
            q2 = fminf(fmaxf(q2, -30.f), 30.f);
            q3 = fminf(fmaxf(q3, -30.f), 30.f);
            const float ig = 1.f / (1.f + __expf(-q0));
            const float fg = 1.f / (1.f + __expf(-q1));
            const float te = __expf(2.f * q2);
            const float gg = (te - 1.f) / (te + 1.f);
            const float og = 1.f / (1.f + __expf(-q3));
            float cs = (c == 0) ? cs0 : cs1;
            cs = fg * cs + ig * gg;
            const float csc = fminf(fmaxf(cs, -15.f), 15.f);
            const float t2 = __expf(2.f * csc);
            const float th = (t2 - 1.f) / (t2 + 1.f);
            const float h = og * th;
            if (c == 0) { cs0 = cs; hv0 = h; } else { cs1 = cs; hv1 = h; }
        }

        if (s < TT - 1) {
            // ---- publish h FIRST (relaxed agent store, write-through) ----
            {
                bf16 hb0 = f2bf(hv0), hb1 = f2bf(hv1);
                unsigned pk = (unsigned)*(unsigned short*)&hb0 |
                              ((unsigned)*(unsigned short*)&hb1 << 16);
                unsigned* hp = (unsigned*)(hsl + (size_t)((s + 1) & 1) * BH + (size_t)mC * HH + j0 + jjA);
                __hip_atomic_store(hp, pk, __ATOMIC_RELAXED, __HIP_MEMORY_SCOPE_AGENT);
            }
            asm volatile("s_waitcnt vmcnt(0)" ::: "memory");  // publish visible
            __syncthreads();                                   // whole WG published
            if (tid == 0)
                __hip_atomic_store(barsd + wgl * 32, (unsigned)(s + 1),
                                   __ATOMIC_RELAXED, __HIP_MEMORY_SCOPE_AGENT);

            // ---- spin-window work: dout store + next gx prefetch ----
            {
                float2 ho; ho.x = hv0; ho.y = hv1;
                *(float2*)(dout + ((size_t)mC * TT + t_x) * (2 * HH) + (size_t)dir * HH + j0 + jjA) = ho;
            }
            const int t_n = dir ? (TT - 2 - s) : (s + 1);
            unsigned gwn[4];
#pragma unroll
            for (int gg = 0; gg < 4; ++gg)
                gwn[gg] = gxw[((size_t)(t_n * 4 + gg) * 128 + cg) * 64 + l];

            // ---- per-wave parallel poll of all 16 WG flags ----
            {
                const unsigned tgt = (unsigned)(s + 1);
                const int fl = l & 15;
                while (true) {
                    unsigned v = __hip_atomic_load(barsd + fl * 32,
                                                   __ATOMIC_RELAXED, __HIP_MEMORY_SCOPE_AGENT);
                    if (__all(v >= tgt)) break;
                    __builtin_amdgcn_s_sleep(1);
                }
            }

            // ---- restage h slot (s+1)&1: sc0 sc1 loads (L1/L2 bypass) ----
            {
                const u32x4* src = (const u32x4*)(hsl + (size_t)((s + 1) & 1) * BH);
                u32x4 vv[4];
#pragma unroll
                for (int q = 0; q < 4; ++q) {
                    const u32x4* p = src + (q * 512 + tid);
                    asm volatile("global_load_dwordx4 %0, %1, off sc0 sc1"
                                 : "=v"(vv[q]) : "v"(p));
                }
                asm volatile("s_waitcnt vmcnt(0)" ::: "memory");
#pragma unroll
                for (int q = 0; q < 4; ++q) {
                    const int e = (q * 512 + tid) * 8;
                    *(u32x4*)&h_s[e >> 9][e & 511] = vv[q];
                }
            }
            __syncthreads();
#pragma unroll
            for (int gg = 0; gg < 4; ++gg) gw[gg] = gwn[gg];
        } else {
            // ---- last step: dout + h_n/c_n ----
            float2 ho; ho.x = hv0; ho.y = hv1;
            *(float2*)(dout + ((size_t)mC * TT + t_x) * (2 * HH) + (size_t)dir * HH + j0 + jjA) = ho;
            const size_t hn_off = (size_t)BB * TT * 2 * HH;
            float2 co; co.x = cs0; co.y = cs1;
            *(float2*)(dout + hn_off + (size_t)dir * BH + (size_t)mC * HH + j0 + jjA) = ho;
            *(float2*)(dout + hn_off + 2 * (size_t)BH + (size_t)dir * BH + (size_t)mC * HH + j0 + jjA) = co;
        }
    }
}

// ---------------------------------------------------------------------------
extern "C" void kernel_launch(void* const* d_in, const int* in_sizes, int n_in,
                              void* d_out, int out_size, void* d_ws, size_t ws_size,
                              hipStream_t stream)
{
    (void)in_sizes; (void)n_in; (void)out_size;
    const float* x     = (const float*)d_in[0];
    const float* h0    = (const float*)d_in[1];
    const float* c0    = (const float*)d_in[2];
    const float* wih_f = (const float*)d_in[3];
    const float* whh_f = (const float*)d_in[4];
    const float* bih_f = (const float*)d_in[5];
    const float* bhh_f = (const float*)d_in[6];
    const float* wih_r = (const float*)d_in[7];
    const float* whh_r = (const float*)d_in[8];
    const float* bih_r = (const float*)d_in[9];
    const float* bhh_r = (const float*)d_in[10];
    float* out = (float*)d_out;

    const size_t gx1 = GX1 * sizeof(bf16);                   // 64 MB per direction
    const size_t needA = 2 * gx1 + (size_t)4 * BH * sizeof(bf16) + 4096;
    char* ws = (char*)d_ws;

    if (ws_size >= needA) {
        // Plan A: both directions concurrently (32 8-wave WGs).
        bf16* gx = (bf16*)ws;
        bf16* h_buf = (bf16*)(ws + 2 * gx1);
        unsigned int* bars = (unsigned int*)(ws + 2 * gx1 + (size_t)4 * BH * sizeof(bf16));
        hipMemsetAsync(bars, 0, 4096, stream);
        dim3 g1(MM / 64, G4 / 128, 2);
        proj_mfma_kernel<<<g1, 256, 0, stream>>>(x, wih_f, wih_r, bih_f, bhh_f, bih_r, bhh_r, gx, 0);
        lstm_rec_kernel<<<dim3(2 * WGD), dim3(512), 0, stream>>>(
            gx, h0, c0, whh_f, whh_r, out, h_buf, bars, 0);
    } else {
        // Plan B: sequential per-direction, single 64 MB gx buffer reused.
        bf16* gx = (bf16*)ws;
        bf16* h_buf = (bf16*)(ws + gx1);
        unsigned int* bars = (unsigned int*)(ws + gx1 + (size_t)2 * BH * sizeof(bf16));
        for (int d = 0; d < 2; ++d) {
            hipMemsetAsync(bars, 0, 2048, stream);
            dim3 g1(MM / 64, G4 / 128, 1);
            proj_mfma_kernel<<<g1, 256, 0, stream>>>(x, wih_f, wih_r, bih_f, bhh_f, bih_r, bhh_r, gx, d);
            lstm_rec_kernel<<<dim3(WGD), dim3(512), 0, stream>>>(
                gx, h0, c0, whh_f, whh_r, out, h_buf, bars, d);
        }
    }
}

// Round 3
// 2263.994 us; speedup vs baseline: 1.0173x; 1.0173x over previous
//
#include <hip/hip_runtime.h>
#include <hip/hip_bf16.h>
#include <math.h>
#include <stdint.h>

#define BB 32
#define TT 512
#define II 512
#define HH 512
#define G4 (4 * HH)      // 2048
#define MM (TT * BB)     // 16384 rows of gx per direction
#define BH (BB * HH)     // 16384
#define WGD 32           // workgroups per direction in rec kernel (4 waves each)

#define SLOTS 8          // h-exchange ring depth (reclaim barrier every SLOTS steps)
#define PAIRS 8192       // h-pairs per slot: BH/2 (each pair = 2 bf16 packed + tag)
#define RING1 ((size_t)SLOTS * PAIRS * 8)   // bytes per direction = 512 KB

typedef __hip_bfloat16 bf16;
typedef __attribute__((ext_vector_type(8))) short short8;   // 8 bf16 = 4 VGPRs
typedef __attribute__((ext_vector_type(4))) float f32x4;    // MFMA accumulator
typedef __attribute__((ext_vector_type(4))) unsigned u32x4; // for asm loads

__device__ __forceinline__ float bf2f(bf16 v) { return __bfloat162float(v); }
__device__ __forceinline__ bf16  f2bf(float v) { return __float2bfloat16(v); }
__device__ __forceinline__ short f2bs(float x) { bf16 v = f2bf(x); return *reinterpret_cast<short*>(&v); }
__device__ __forceinline__ float bs2f(short s) {
    unsigned u = ((unsigned)(unsigned short)s) << 16;
    return __uint_as_float(u);
}
__device__ __forceinline__ short8 pk8(float4 u, float4 v) {
    short8 t;
    t[0] = f2bs(u.x); t[1] = f2bs(u.y); t[2] = f2bs(u.z); t[3] = f2bs(u.w);
    t[4] = f2bs(v.x); t[5] = f2bs(v.y); t[6] = f2bs(v.z); t[7] = f2bs(v.w);
    return t;
}

// gx gate-planar swizzle: [dl][t][g][cg 0..127][b*4 + jj] bf16
#define GX1 ((size_t)TT * 4 * 128 * 128)   // elements per direction (= MM*G4)

// ---------------------------------------------------------------------------
// Phase 1: input projection GEMM via MFMA (bf16 in / fp32 acc). Unchanged.
// ---------------------------------------------------------------------------
__global__ __launch_bounds__(256) void proj_mfma_kernel(
    const float* __restrict__ x,
    const float* __restrict__ w_f, const float* __restrict__ w_r,
    const float* __restrict__ bi_f, const float* __restrict__ bh_f,
    const float* __restrict__ bi_r, const float* __restrict__ bh_r,
    bf16* __restrict__ gx, int dir0)
{
    const int dl = blockIdx.z, dir = dir0 + dl;
    const int m0 = blockIdx.x * 64;
    const int n0 = blockIdx.y * 128;
    const float* __restrict__ w  = dir ? w_r  : w_f;
    const float* __restrict__ bi = dir ? bi_r : bi_f;
    const float* __restrict__ bh = dir ? bh_r : bh_f;

    __shared__ __align__(16) char smem[17408];
    bf16 (*As)[40]  = (bf16(*)[40])smem;            // 64 x (32+8 pad)
    bf16 (*Bs)[40]  = (bf16(*)[40])(smem + 5120);   // 128 x (32+8 pad)
    bf16 (*Cs)[136] = (bf16(*)[136])smem;           // 64 x 136 (reuses smem)

    const int tid = threadIdx.x;
    const int wv = tid >> 6, l = tid & 63;
    const int nl = l & 15, ko = (l >> 4) * 8;

    const int a_r = tid >> 2, a_s = tid & 3;
    const float* a_src = x + ((size_t)((m0 + a_r) & 31) * TT + (size_t)((m0 + a_r) >> 5)) * II + a_s * 8;
    const int b_r = tid >> 1, b_h = tid & 1;
    const float* b_src = w + (size_t)(n0 + b_r) * II + b_h * 16;

    f32x4 acc[8];
#pragma unroll
    for (int j = 0; j < 8; ++j) acc[j] = (f32x4){0.f, 0.f, 0.f, 0.f};

    float bias[8];
#pragma unroll
    for (int j = 0; j < 8; ++j) {
        const int n = n0 + j * 16 + nl;
        bias[j] = bi[n] + bh[n];
    }

    for (int k0 = 0; k0 < II; k0 += 32) {
        const float4 av0 = *(const float4*)(a_src + k0);
        const float4 av1 = *(const float4*)(a_src + k0 + 4);
        const float4 bv0 = *(const float4*)(b_src + k0);
        const float4 bv1 = *(const float4*)(b_src + k0 + 4);
        const float4 bv2 = *(const float4*)(b_src + k0 + 8);
        const float4 bv3 = *(const float4*)(b_src + k0 + 12);
        __syncthreads();   // previous tile fully consumed
        *(short8*)&As[a_r][a_s * 8] = pk8(av0, av1);
        *(short8*)&Bs[b_r][b_h * 16]     = pk8(bv0, bv1);
        *(short8*)&Bs[b_r][b_h * 16 + 8] = pk8(bv2, bv3);
        __syncthreads();
        const short8 a = *(const short8*)&As[wv * 16 + nl][ko];
#pragma unroll
        for (int j = 0; j < 8; ++j) {
            const short8 b = *(const short8*)&Bs[j * 16 + nl][ko];
            acc[j] = __builtin_amdgcn_mfma_f32_16x16x32_bf16(a, b, acc[j], 0, 0, 0);
        }
    }

    __syncthreads();
    const int row0 = (l >> 4) * 4;
#pragma unroll
    for (int j = 0; j < 8; ++j)
#pragma unroll
        for (int r = 0; r < 4; ++r)
            Cs[wv * 16 + row0 + r][j * 16 + nl] = f2bf(acc[j][r] + bias[j]);
    __syncthreads();

    bf16* gxd = gx + (size_t)dl * GX1;
    const int g   = n0 >> 9;
    const int cgb = (n0 & 511) >> 2;
    const int t_base = blockIdx.x * 2;
#pragma unroll
    for (int i = 0; i < 4; ++i) {
        const int c = i * 256 + tid;
        const int tl = c >> 9, cgl = (c >> 4) & 31, u = c & 15;
        const int r0 = tl * 32 + 2 * u;
        const uint2 lo = *(const uint2*)&Cs[r0][cgl * 4];
        const uint2 hi = *(const uint2*)&Cs[r0 + 1][cgl * 4];
        uint4 ov; ov.x = lo.x; ov.y = lo.y; ov.z = hi.x; ov.w = hi.y;
        *(uint4*)(gxd + ((((size_t)(t_base + tl) * 4 + g) * 128 + cgb + cgl) * 128 + u * 8)) = ov;
    }
}

// ---------------------------------------------------------------------------
// Phase 2: MFMA recurrence. Round-8 (tagged-ring exchange):
//  - back to the measured-best 32 WGs/dir x 4 waves (256 thr) config.
//  - h exchange via 8-slot ring of (h32|tag32) 8-byte atomic pairs: the
//    restage load IS the arrival detection (one MALL round trip instead of
//    publish-drain + flag + data = three). Publisher is fire-and-forget.
//  - tags are the step index (monotonic, equality-checked): stale residue
//    from earlier launches/slot reuse can never false-positive.
//  - own-WG columns never read back: each thread rewrites its own pair into
//    LDS from registers.
//  - ring reclaim safety: full counter-barrier (round-0 scheme) every 8
//    steps; bounds skew to <8 iterations so a slot is never overwritten
//    while still being polled.
// ---------------------------------------------------------------------------
__global__ __launch_bounds__(256, 1) void lstm_rec_kernel(
    const bf16* __restrict__ gx,
    const float* __restrict__ h0, const float* __restrict__ c0,
    const float* __restrict__ whh_f, const float* __restrict__ whh_r,
    float* __restrict__ dout,
    unsigned long long* __restrict__ ring,   // [ndir][SLOTS][PAIRS] (h32|tag32)
    unsigned int* __restrict__ bars,         // [ndir][4 counters x 64 uints]
    int dir0)
{
    const int dl  = blockIdx.x >> 5;
    const int wgl = blockIdx.x & 31;
    const int dir = dir0 + dl;
    const int tid = threadIdx.x;
    const int wv  = tid >> 6;            // wave 0..3
    const int l   = tid & 63;            // lane
    const int cg  = wgl * 4 + wv;        // col-group 0..127
    const int j0  = cg * 4;
    const float* __restrict__ whh = dir ? whh_r : whh_f;
    unsigned long long* ringd = ring + (size_t)dl * SLOTS * PAIRS;
    unsigned int* barsd = bars + (size_t)dl * 256;

    __shared__ __align__(16) bf16 h_s[32][520];   // staged h, +8 pad
    __shared__ __align__(16) float ex[4][16][36]; // per-wave gate exchange

    const int nl = l & 15;                // packed col index = gate*4 + jj
    const int g  = nl >> 2, jj = nl & 3;
    const int ko = (l >> 4) * 8;          // k-octet within a K=32 MFMA step

    // ---- B fragments (w_hh) resident in registers ----
    short8 bfrag[16];
    {
        const float* wr = whh + ((size_t)g * HH + (size_t)(j0 + jj)) * HH;
#pragma unroll
        for (int ks = 0; ks < 16; ++ks) {
            const float* p = wr + ks * 32 + ko;
            short8 t;
#pragma unroll
            for (int i = 0; i < 8; ++i) t[i] = f2bs(p[i]);
            bfrag[ks] = t;
        }
    }

    const int mC  = l >> 1;
    const int jjA = (l & 1) * 2;
    const int pc_own = cg * 2 + (l & 1);                 // pair-col this thread publishes
    const bool own_col = (((tid & 127) >> 2) == wgl);    // restage covers own WG's columns?

    float cs0, cs1;
    {
        const float* cp = c0 + (size_t)dir * BH + (size_t)mC * HH + j0 + jjA;
        cs0 = cp[0]; cs1 = cp[1];
    }

    const unsigned* gxw = (const unsigned*)(gx + (size_t)dl * GX1);

    // ---- stage initial h (fp32 h0 -> bf16 LDS) ----
    for (int q = 0; q < 64; ++q) {
        const int f = q * 256 + tid;
        h_s[f >> 9][f & 511] = f2bf(h0[(size_t)dir * BH + f]);
    }
    __syncthreads();

    // first gx fetch: 4 gate-planar dwords (2 cells each)
    unsigned gw[4];
    {
        const int t0 = dir ? (TT - 1) : 0;
#pragma unroll
        for (int gg = 0; gg < 4; ++gg)
            gw[gg] = gxw[((size_t)(t0 * 4 + gg) * 128 + cg) * 64 + l];
    }

#pragma unroll 1
    for (int s = 0; s < TT; ++s) {
        const int t_x = dir ? (TT - 1 - s) : s;

        // ---- MFMA: gates[32 x 16packed] = h . W^T, A from LDS ----
        f32x4 acc0 = {0.f, 0.f, 0.f, 0.f};
        f32x4 acc1 = {0.f, 0.f, 0.f, 0.f};
#pragma unroll
        for (int half = 0; half < 2; ++half) {
            short8 a0[8], a1[8];
#pragma unroll
            for (int k = 0; k < 8; ++k) {
                const int ks = half * 8 + k;
                a0[k] = *(const short8*)&h_s[nl][ks * 32 + ko];
                a1[k] = *(const short8*)&h_s[nl + 16][ks * 32 + ko];
            }
#pragma unroll
            for (int k = 0; k < 8; ++k) {
                acc0 = __builtin_amdgcn_mfma_f32_16x16x32_bf16(a0[k], bfrag[half * 8 + k], acc0, 0, 0, 0);
                acc1 = __builtin_amdgcn_mfma_f32_16x16x32_bf16(a1[k], bfrag[half * 8 + k], acc1, 0, 0, 0);
            }
        }

        // ---- exchange C-layout -> cell layout through per-wave LDS slice ----
        // (wave-local: written and read by the same wave; no barrier needed)
        {
            const int row0 = (l >> 4) * 4;
            *(f32x4*)&ex[wv][nl][row0]      = acc0;
            *(f32x4*)&ex[wv][nl][16 + row0] = acc1;
        }

        float hv0, hv1;
#pragma unroll
        for (int c = 0; c < 2; ++c) {
            const int jc = jjA + c;
            const int sh = 16 * c;
            float q0 = ex[wv][0 * 4 + jc][mC] + bs2f((short)(gw[0] >> sh));
            float q1 = ex[wv][1 * 4 + jc][mC] + bs2f((short)(gw[1] >> sh));
            float q2 = ex[wv][2 * 4 + jc][mC] + bs2f((short)(gw[2] >> sh));
            float q3 = ex[wv][3 * 4 + jc][mC] + bs2f((short)(gw[3] >> sh));
            q0 = fminf(fmaxf(q0, -30.f), 30.f);
            q1 = fminf(fmaxf(q1, -30.f), 30.f);
            q2 = fminf(fmaxf(q2, -30.f), 30.f);
            q3 = fminf(fmaxf(q3, -30.f), 30.f);
            const float ig = 1.f / (1.f + __expf(-q0));
            const float fg = 1.f / (1.f + __expf(-q1));
            const float te = __expf(2.f * q2);
            const float gg = (te - 1.f) / (te + 1.f);
            const float og = 1.f / (1.f + __expf(-q3));
            float cs = (c == 0) ? cs0 : cs1;
            cs = fg * cs + ig * gg;
            const float csc = fminf(fmaxf(cs, -15.f), 15.f);
            const float t2 = __expf(2.f * csc);
            const float th = (t2 - 1.f) / (t2 + 1.f);
            const float h = og * th;
            if (c == 0) { cs0 = cs; hv0 = h; } else { cs1 = cs; hv1 = h; }
        }

        // all waves' MFMA reads of h_s are done before anyone overwrites it
        __syncthreads();

        if (s < TT - 1) {
            // ---- publish tagged h pair: ONE fire-and-forget 8B atomic ----
            unsigned pk;
            {
                bf16 hb0 = f2bf(hv0), hb1 = f2bf(hv1);
                pk = (unsigned)*(unsigned short*)&hb0 |
                     ((unsigned)*(unsigned short*)&hb1 << 16);
                const unsigned long long pk64 =
                    (unsigned long long)pk | ((unsigned long long)(unsigned)(s + 1) << 32);
                unsigned long long* hp =
                    ringd + (size_t)((s + 1) & (SLOTS - 1)) * PAIRS + (size_t)mC * 256 + pc_own;
                __hip_atomic_store(hp, pk64, __ATOMIC_RELAXED, __HIP_MEMORY_SCOPE_AGENT);
            }

            // ---- latency-window work: dout store + next gx prefetch ----
            {
                float2 ho; ho.x = hv0; ho.y = hv1;
                *(float2*)(dout + ((size_t)mC * TT + t_x) * (2 * HH) + (size_t)dir * HH + j0 + jjA) = ho;
            }
            const int t_n = dir ? (TT - 2 - s) : (s + 1);
            unsigned gwn[4];
#pragma unroll
            for (int gg = 0; gg < 4; ++gg)
                gwn[gg] = gxw[((size_t)(t_n * 4 + gg) * 128 + cg) * 64 + l];

            // ---- poll-restage: tagged loads ARE the arrival detection ----
            {
                const unsigned expt = (unsigned)(s + 1);
                const char* sb = (const char*)(ringd + (size_t)((s + 1) & (SLOTS - 1)) * PAIRS)
                                 + (size_t)tid * 16;
                const int row_h = tid >> 7;           // row parity
                const int bcol  = 4 * (tid & 127);    // bf16 col of first h-word
                u32x4 vv[16];
                unsigned need = own_col ? 0u : 0xffffu;
                while (need) {
#pragma unroll
                    for (int q = 0; q < 16; ++q) {
                        if (need & (1u << q)) {
                            const char* p = sb + q * 4096;
                            asm volatile("global_load_dwordx4 %0, %1, off sc0 sc1"
                                         : "=v"(vv[q]) : "v"(p));
                        }
                    }
                    asm volatile("s_waitcnt vmcnt(0)" ::: "memory");
#pragma unroll
                    for (int q = 0; q < 16; ++q) {
                        if (need & (1u << q)) {
                            if (vv[q][1] == expt && vv[q][3] == expt) {
                                uint2 o; o.x = vv[q][0]; o.y = vv[q][2];
                                *(uint2*)&h_s[2 * q + row_h][bcol] = o;
                                need &= ~(1u << q);
                            }
                        }
                    }
                }
                // own columns straight from registers (never read back)
                *(unsigned*)&h_s[mC][j0 + jjA] = pk;
            }
            __syncthreads();

            // ---- ring reclaim barrier, every SLOTS steps (amortized) ----
            if (((s + 1) & (SLOTS - 1)) == 0) {
                if (tid == 0)
                    __hip_atomic_fetch_add(barsd + (wgl & 3) * 64, 1u,
                                           __ATOMIC_RELAXED, __HIP_MEMORY_SCOPE_AGENT);
                if (wv == 0 && l < 4) {
                    const unsigned tgt = (unsigned)(WGD / 4) * (unsigned)((s + 1) >> 3);
                    while (__hip_atomic_load(barsd + l * 64,
                                             __ATOMIC_RELAXED, __HIP_MEMORY_SCOPE_AGENT) < tgt) {
                        __builtin_amdgcn_s_sleep(1);
                    }
                }
                __syncthreads();
            }

#pragma unroll
            for (int gg = 0; gg < 4; ++gg) gw[gg] = gwn[gg];
        } else {
            // ---- last step: dout + h_n/c_n ----
            float2 ho; ho.x = hv0; ho.y = hv1;
            *(float2*)(dout + ((size_t)mC * TT + t_x) * (2 * HH) + (size_t)dir * HH + j0 + jjA) = ho;
            const size_t hn_off = (size_t)BB * TT * 2 * HH;
            float2 co; co.x = cs0; co.y = cs1;
            *(float2*)(dout + hn_off + (size_t)dir * BH + (size_t)mC * HH + j0 + jjA) = ho;
            *(float2*)(dout + hn_off + 2 * (size_t)BH + (size_t)dir * BH + (size_t)mC * HH + j0 + jjA) = co;
        }
    }
}

// ---------------------------------------------------------------------------
extern "C" void kernel_launch(void* const* d_in, const int* in_sizes, int n_in,
                              void* d_out, int out_size, void* d_ws, size_t ws_size,
                              hipStream_t stream)
{
    (void)in_sizes; (void)n_in; (void)out_size;
    const float* x     = (const float*)d_in[0];
    const float* h0    = (const float*)d_in[1];
    const float* c0    = (const float*)d_in[2];
    const float* wih_f = (const float*)d_in[3];
    const float* whh_f = (const float*)d_in[4];
    const float* bih_f = (const float*)d_in[5];
    const float* bhh_f = (const float*)d_in[6];
    const float* wih_r = (const float*)d_in[7];
    const float* whh_r = (const float*)d_in[8];
    const float* bih_r = (const float*)d_in[9];
    const float* bhh_r = (const float*)d_in[10];
    float* out = (float*)d_out;

    const size_t gx1 = GX1 * sizeof(bf16);                   // 64 MB per direction
    const size_t needA = 2 * gx1 + 2 * RING1 + 8192;
    char* ws = (char*)d_ws;

    if (ws_size >= needA) {
        // Plan A: both directions concurrently (64 4-wave WGs).
        bf16* gx = (bf16*)ws;
        unsigned long long* ring = (unsigned long long*)(ws + 2 * gx1);
        unsigned int* bars = (unsigned int*)(ws + 2 * gx1 + 2 * RING1);
        hipMemsetAsync(ring, 0, 2 * RING1 + 4096, stream);
        dim3 g1(MM / 64, G4 / 128, 2);
        proj_mfma_kernel<<<g1, 256, 0, stream>>>(x, wih_f, wih_r, bih_f, bhh_f, bih_r, bhh_r, gx, 0);
        lstm_rec_kernel<<<dim3(2 * WGD), dim3(256), 0, stream>>>(
            gx, h0, c0, whh_f, whh_r, out, ring, bars, 0);
    } else {
        // Plan B: sequential per-direction, single 64 MB gx buffer reused.
        bf16* gx = (bf16*)ws;
        unsigned long long* ring = (unsigned long long*)(ws + gx1);
        unsigned int* bars = (unsigned int*)(ws + gx1 + RING1);
        for (int d = 0; d < 2; ++d) {
            hipMemsetAsync(ring, 0, RING1 + 4096, stream);
            dim3 g1(MM / 64, G4 / 128, 1);
            proj_mfma_kernel<<<g1, 256, 0, stream>>>(x, wih_f, wih_r, bih_f, bhh_f, bih_r, bhh_r, gx, d);
            lstm_rec_kernel<<<dim3(WGD), dim3(256), 0, stream>>>(
                gx, h0, c0, whh_f, whh_r, out, ring, bars, d);
        }
    }
}

// Round 5
// 2210.561 us; speedup vs baseline: 1.0419x; 1.0242x over previous
//
#include <hip/hip_runtime.h>
#include <hip/hip_bf16.h>
#include <math.h>
#include <stdint.h>

#define BB 32
#define TT 512
#define II 512
#define HH 512
#define G4 (4 * HH)      // 2048
#define MM (TT * BB)     // 16384 rows of gx per direction
#define BH (BB * HH)     // 16384
#define WGD 32           // workgroups per direction in rec kernel (4 waves each)

#define SLOT_DW (BH / 2)                       // 8192 pair-dwords per slot
#define RING_DW ((size_t)TT * SLOT_DW)         // 512 slots per direction (write-once)
#define RING_BYTES (RING_DW * 4)               // 16 MB per direction
#define NANP 0x7FC0u                           // bf16 qNaN sentinel (low half check)

typedef __hip_bfloat16 bf16;
typedef __attribute__((ext_vector_type(8))) short short8;   // 8 bf16 = 4 VGPRs
typedef __attribute__((ext_vector_type(4))) float f32x4;    // MFMA accumulator
typedef __attribute__((ext_vector_type(4))) unsigned u32x4; // for asm loads

__device__ __forceinline__ float bf2f(bf16 v) { return __bfloat162float(v); }
__device__ __forceinline__ bf16  f2bf(float v) { return __float2bfloat16(v); }
__device__ __forceinline__ short f2bs(float x) { bf16 v = f2bf(x); return *reinterpret_cast<short*>(&v); }
__device__ __forceinline__ float bs2f(short s) {
    unsigned u = ((unsigned)(unsigned short)s) << 16;
    return __uint_as_float(u);
}
__device__ __forceinline__ short8 pk8(float4 u, float4 v) {
    short8 t;
    t[0] = f2bs(u.x); t[1] = f2bs(u.y); t[2] = f2bs(u.z); t[3] = f2bs(u.w);
    t[4] = f2bs(v.x); t[5] = f2bs(v.y); t[6] = f2bs(v.z); t[7] = f2bs(v.w);
    return t;
}

// gx gate-planar swizzle: [dl][t][g][cg 0..127][b*4 + jj] bf16
#define GX1 ((size_t)TT * 4 * 128 * 128)   // elements per direction (= MM*G4)

// ---------------------------------------------------------------------------
// Phase 1: input projection GEMM via MFMA (bf16 in / fp32 acc). Unchanged.
// ---------------------------------------------------------------------------
__global__ __launch_bounds__(256) void proj_mfma_kernel(
    const float* __restrict__ x,
    const float* __restrict__ w_f, const float* __restrict__ w_r,
    const float* __restrict__ bi_f, const float* __restrict__ bh_f,
    const float* __restrict__ bi_r, const float* __restrict__ bh_r,
    bf16* __restrict__ gx, int dir0)
{
    const int dl = blockIdx.z, dir = dir0 + dl;
    const int m0 = blockIdx.x * 64;
    const int n0 = blockIdx.y * 128;
    const float* __restrict__ w  = dir ? w_r  : w_f;
    const float* __restrict__ bi = dir ? bi_r : bi_f;
    const float* __restrict__ bh = dir ? bh_r : bh_f;

    __shared__ __align__(16) char smem[17408];
    bf16 (*As)[40]  = (bf16(*)[40])smem;            // 64 x (32+8 pad)
    bf16 (*Bs)[40]  = (bf16(*)[40])(smem + 5120);   // 128 x (32+8 pad)
    bf16 (*Cs)[136] = (bf16(*)[136])smem;           // 64 x 136 (reuses smem)

    const int tid = threadIdx.x;
    const int wv = tid >> 6, l = tid & 63;
    const int nl = l & 15, ko = (l >> 4) * 8;

    const int a_r = tid >> 2, a_s = tid & 3;
    const float* a_src = x + ((size_t)((m0 + a_r) & 31) * TT + (size_t)((m0 + a_r) >> 5)) * II + a_s * 8;
    const int b_r = tid >> 1, b_h = tid & 1;
    const float* b_src = w + (size_t)(n0 + b_r) * II + b_h * 16;

    f32x4 acc[8];
#pragma unroll
    for (int j = 0; j < 8; ++j) acc[j] = (f32x4){0.f, 0.f, 0.f, 0.f};

    float bias[8];
#pragma unroll
    for (int j = 0; j < 8; ++j) {
        const int n = n0 + j * 16 + nl;
        bias[j] = bi[n] + bh[n];
    }

    for (int k0 = 0; k0 < II; k0 += 32) {
        const float4 av0 = *(const float4*)(a_src + k0);
        const float4 av1 = *(const float4*)(a_src + k0 + 4);
        const float4 bv0 = *(const float4*)(b_src + k0);
        const float4 bv1 = *(const float4*)(b_src + k0 + 4);
        const float4 bv2 = *(const float4*)(b_src + k0 + 8);
        const float4 bv3 = *(const float4*)(b_src + k0 + 12);
        __syncthreads();   // previous tile fully consumed
        *(short8*)&As[a_r][a_s * 8] = pk8(av0, av1);
        *(short8*)&Bs[b_r][b_h * 16]     = pk8(bv0, bv1);
        *(short8*)&Bs[b_r][b_h * 16 + 8] = pk8(bv2, bv3);
        __syncthreads();
        const short8 a = *(const short8*)&As[wv * 16 + nl][ko];
#pragma unroll
        for (int j = 0; j < 8; ++j) {
            const short8 b = *(const short8*)&Bs[j * 16 + nl][ko];
            acc[j] = __builtin_amdgcn_mfma_f32_16x16x32_bf16(a, b, acc[j], 0, 0, 0);
        }
    }

    __syncthreads();
    const int row0 = (l >> 4) * 4;
#pragma unroll
    for (int j = 0; j < 8; ++j)
#pragma unroll
        for (int r = 0; r < 4; ++r)
            Cs[wv * 16 + row0 + r][j * 16 + nl] = f2bf(acc[j][r] + bias[j]);
    __syncthreads();

    bf16* gxd = gx + (size_t)dl * GX1;
    const int g   = n0 >> 9;
    const int cgb = (n0 & 511) >> 2;
    const int t_base = blockIdx.x * 2;
#pragma unroll
    for (int i = 0; i < 4; ++i) {
        const int c = i * 256 + tid;
        const int tl = c >> 9, cgl = (c >> 4) & 31, u = c & 15;
        const int r0 = tl * 32 + 2 * u;
        const uint2 lo = *(const uint2*)&Cs[r0][cgl * 4];
        const uint2 hi = *(const uint2*)&Cs[r0 + 1][cgl * 4];
        uint4 ov; ov.x = lo.x; ov.y = lo.y; ov.z = hi.x; ov.w = hi.y;
        *(uint4*)(gxd + ((((size_t)(t_base + tl) * 4 + g) * 128 + cgb + cgl) * 128 + u * 8)) = ov;
    }
}

// ---------------------------------------------------------------------------
// Phase 2: MFMA recurrence. Round-10 (write-once NaN-sentinel ring):
//  - one 32KB slot PER TIMESTEP (no reuse): ring NaN-filled once at start
//    (behind the round-0-proven counter barrier, the only barrier in the
//    kernel), then each dword written AT MOST ONCE. A non-NaN read is
//    unconditionally fresh: no tags, no refills, no window barriers, no ABA.
//  - publish is one fire-and-forget 4B agent atomic store; the poll-restage
//    load IS the arrival detection: ONE MALL round trip per step on the
//    critical path instead of round-0's three (drain + counter + restage).
//  - skew is self-limited to <=1 step: slot s+1 only completes when every
//    WG published step s.
//  - dout store + next-step gx prefetch issued before the poll to hide in
//    the arrival window. Own-WG columns rewritten from registers, not read.
// ---------------------------------------------------------------------------
__global__ __launch_bounds__(256, 1) void lstm_rec_kernel(
    const bf16* __restrict__ gx,
    const float* __restrict__ h0, const float* __restrict__ c0,
    const float* __restrict__ whh_f, const float* __restrict__ whh_r,
    float* __restrict__ dout,
    unsigned* __restrict__ ring,       // [ndir][TT slots][SLOT_DW] write-once
    unsigned int* __restrict__ bars,   // [ndir][4 counters x 64 uints]
    int dir0)
{
    const int dl  = blockIdx.x >> 5;
    const int wgl = blockIdx.x & 31;
    const int dir = dir0 + dl;
    const int tid = threadIdx.x;
    const int wv  = tid >> 6;            // wave 0..3
    const int l   = tid & 63;            // lane
    const int cg  = wgl * 4 + wv;        // col-group 0..127
    const int j0  = cg * 4;
    const float* __restrict__ whh = dir ? whh_r : whh_f;
    unsigned* ringd = ring + (size_t)dl * RING_DW;
    unsigned int* barsd = bars + (size_t)dl * 256;

    __shared__ __align__(16) bf16 h_s[32][520];   // staged h, +8 pad
    __shared__ __align__(16) float ex[4][16][36]; // per-wave gate exchange

    const int nl = l & 15;                // packed col index = gate*4 + jj
    const int g  = nl >> 2, jj = nl & 3;
    const int ko = (l >> 4) * 8;          // k-octet within a K=32 MFMA step

    // ---- B fragments (w_hh) resident in registers ----
    short8 bfrag[16];
    {
        const float* wr = whh + ((size_t)g * HH + (size_t)(j0 + jj)) * HH;
#pragma unroll
        for (int ks = 0; ks < 16; ++ks) {
            const float* p = wr + ks * 32 + ko;
            short8 t;
#pragma unroll
            for (int i = 0; i < 8; ++i) t[i] = f2bs(p[i]);
            bfrag[ks] = t;
        }
    }

    const int mC  = l >> 1;
    const int jjA = (l & 1) * 2;
    const int poff = mC * 256 + ((j0 + jjA) >> 1);   // own pair dword offset in a slot

    float cs0, cs1;
    {
        const float* cp = c0 + (size_t)dir * BH + (size_t)mC * HH + j0 + jjA;
        cs0 = cp[0]; cs1 = cp[1];
    }

    const unsigned* gxw = (const unsigned*)(gx + (size_t)dl * GX1);

    // ---- stage initial h (fp32 h0 -> bf16 LDS) ----
    for (int q = 0; q < 64; ++q) {
        const int f = q * 256 + tid;
        h_s[f >> 9][f & 511] = f2bf(h0[(size_t)dir * BH + f]);
    }

    // ---- init: NaN-fill the whole write-once ring (coalesced 8B stores) ----
    {
        unsigned long long* rq = (unsigned long long*)ringd;
        const int gt = wgl * 256 + tid;                      // 0..8191
        const unsigned long long NN = 0x7FC07FC07FC07FC0ull;
#pragma unroll 4
        for (int q = 0; q < 256; ++q)                        // 256*8192 qwords = RING_DW/2
            __hip_atomic_store(rq + (size_t)q * 8192 + gt, NN,
                               __ATOMIC_RELAXED, __HIP_MEMORY_SCOPE_AGENT);
        asm volatile("s_waitcnt vmcnt(0)" ::: "memory");
    }
    __syncthreads();
    // ---- the ONLY cross-WG barrier: round-0-proven counter scheme ----
    if (tid == 0)
        __hip_atomic_fetch_add(barsd + (wgl & 3) * 64, 1u,
                               __ATOMIC_RELAXED, __HIP_MEMORY_SCOPE_AGENT);
    if (wv == 0 && l < 4) {
        while (__hip_atomic_load(barsd + l * 64,
                                 __ATOMIC_RELAXED, __HIP_MEMORY_SCOPE_AGENT) < (unsigned)(WGD / 4)) {
            __builtin_amdgcn_s_sleep(1);
        }
    }
    __syncthreads();

    // first gx fetch: 4 gate-planar dwords (2 cells each)
    unsigned gw[4];
    {
        const int t0 = dir ? (TT - 1) : 0;
#pragma unroll
        for (int gg = 0; gg < 4; ++gg)
            gw[gg] = gxw[((size_t)(t0 * 4 + gg) * 128 + cg) * 64 + l];
    }

    // all 8 of this thread's restage chunks share one column group (tid&63);
    // skip them all iff that column group belongs to this WG (rewritten from regs)
    const unsigned need_init = (((tid & 63) >> 1) == wgl) ? 0u : 0xFFu;

#pragma unroll 1
    for (int s = 0; s < TT; ++s) {
        const int t_x = dir ? (TT - 1 - s) : s;

        // ---- MFMA: gates[32 x 16packed] = h . W^T, A from LDS ----
        f32x4 acc0 = {0.f, 0.f, 0.f, 0.f};
        f32x4 acc1 = {0.f, 0.f, 0.f, 0.f};
#pragma unroll
        for (int half = 0; half < 2; ++half) {
            short8 a0[8], a1[8];
#pragma unroll
            for (int k = 0; k < 8; ++k) {
                const int ks = half * 8 + k;
                a0[k] = *(const short8*)&h_s[nl][ks * 32 + ko];
                a1[k] = *(const short8*)&h_s[nl + 16][ks * 32 + ko];
            }
#pragma unroll
            for (int k = 0; k < 8; ++k) {
                acc0 = __builtin_amdgcn_mfma_f32_16x16x32_bf16(a0[k], bfrag[half * 8 + k], acc0, 0, 0, 0);
                acc1 = __builtin_amdgcn_mfma_f32_16x16x32_bf16(a1[k], bfrag[half * 8 + k], acc1, 0, 0, 0);
            }
        }

        // ---- exchange C-layout -> cell layout through per-wave LDS slice ----
        // (wave-local: written and read by the same wave; no barrier needed)
        {
            const int row0 = (l >> 4) * 4;
            *(f32x4*)&ex[wv][nl][row0]      = acc0;
            *(f32x4*)&ex[wv][nl][16 + row0] = acc1;
        }

        float hv0, hv1;
#pragma unroll
        for (int c = 0; c < 2; ++c) {
            const int jc = jjA + c;
            const int sh = 16 * c;
            float q0 = ex[wv][0 * 4 + jc][mC] + bs2f((short)(gw[0] >> sh));
            float q1 = ex[wv][1 * 4 + jc][mC] + bs2f((short)(gw[1] >> sh));
            float q2 = ex[wv][2 * 4 + jc][mC] + bs2f((short)(gw[2] >> sh));
            float q3 = ex[wv][3 * 4 + jc][mC] + bs2f((short)(gw[3] >> sh));
            q0 = fminf(fmaxf(q0, -30.f), 30.f);
            q1 = fminf(fmaxf(q1, -30.f), 30.f);
            q2 = fminf(fmaxf(q2, -30.f), 30.f);
            q3 = fminf(fmaxf(q3, -30.f), 30.f);
            const float ig = 1.f / (1.f + __expf(-q0));
            const float fg = 1.f / (1.f + __expf(-q1));
            const float te = __expf(2.f * q2);
            const float gg = (te - 1.f) / (te + 1.f);
            const float og = 1.f / (1.f + __expf(-q3));
            float cs = (c == 0) ? cs0 : cs1;
            cs = fg * cs + ig * gg;
            const float csc = fminf(fmaxf(cs, -15.f), 15.f);
            const float t2 = __expf(2.f * csc);
            const float th = (t2 - 1.f) / (t2 + 1.f);
            const float h = og * th;
            if (c == 0) { cs0 = cs; hv0 = h; } else { cs1 = cs; hv1 = h; }
        }

        // all waves' MFMA reads of h_s are done before anyone overwrites it
        __syncthreads();

        if (s < TT - 1) {
            unsigned* slot = ringd + (size_t)(s + 1) * SLOT_DW;

            // ---- publish own h pair: ONE fire-and-forget 4B agent store ----
            unsigned pk;
            {
                bf16 hb0 = f2bf(hv0), hb1 = f2bf(hv1);
                pk = (unsigned)*(unsigned short*)&hb0 |
                     ((unsigned)*(unsigned short*)&hb1 << 16);
                __hip_atomic_store(slot + poff, pk,
                                   __ATOMIC_RELAXED, __HIP_MEMORY_SCOPE_AGENT);
            }

            // ---- arrival-window work: dout store + next gx prefetch ----
            {
                float2 ho; ho.x = hv0; ho.y = hv1;
                *(float2*)(dout + ((size_t)mC * TT + t_x) * (2 * HH) + (size_t)dir * HH + j0 + jjA) = ho;
            }
            const int t_n = dir ? (TT - 2 - s) : (s + 1);
            unsigned gwn[4];
#pragma unroll
            for (int gg = 0; gg < 4; ++gg)
                gwn[gg] = gxw[((size_t)(t_n * 4 + gg) * 128 + cg) * 64 + l];

            // ---- poll-restage: non-NaN pair == fresh (write-once ring) ----
            {
                u32x4 vv[8];
                unsigned need = need_init;
                while (need) {
#pragma unroll
                    for (int q = 0; q < 8; ++q) {
                        if (need & (1u << q)) {
                            const unsigned* p = slot + (q * 256 + tid) * 4;
                            asm volatile("global_load_dwordx4 %0, %1, off sc0 sc1"
                                         : "=v"(vv[q]) : "v"(p));
                        }
                    }
                    asm volatile("s_waitcnt vmcnt(0)" ::: "memory");
#pragma unroll
                    for (int q = 0; q < 8; ++q) {
                        if (need & (1u << q)) {
                            const u32x4 v = vv[q];
                            const bool ok = ((v[0] & 0xffffu) != NANP) &
                                            ((v[1] & 0xffffu) != NANP) &
                                            ((v[2] & 0xffffu) != NANP) &
                                            ((v[3] & 0xffffu) != NANP);
                            if (ok) {
                                const int c = q * 256 + tid;
                                *(u32x4*)&h_s[c >> 6][(c & 63) * 8] = v;
                                need &= ~(1u << q);
                            }
                        }
                    }
                }
                // own columns straight from registers (never read back)
                *(unsigned*)&h_s[mC][j0 + jjA] = pk;
            }
            __syncthreads();
#pragma unroll
            for (int gg = 0; gg < 4; ++gg) gw[gg] = gwn[gg];
        } else {
            // ---- last step: dout + h_n/c_n ----
            float2 ho; ho.x = hv0; ho.y = hv1;
            *(float2*)(dout + ((size_t)mC * TT + t_x) * (2 * HH) + (size_t)dir * HH + j0 + jjA) = ho;
            const size_t hn_off = (size_t)BB * TT * 2 * HH;
            float2 co; co.x = cs0; co.y = cs1;
            *(float2*)(dout + hn_off + (size_t)dir * BH + (size_t)mC * HH + j0 + jjA) = ho;
            *(float2*)(dout + hn_off + 2 * (size_t)BH + (size_t)dir * BH + (size_t)mC * HH + j0 + jjA) = co;
        }
    }
}

// ---------------------------------------------------------------------------
extern "C" void kernel_launch(void* const* d_in, const int* in_sizes, int n_in,
                              void* d_out, int out_size, void* d_ws, size_t ws_size,
                              hipStream_t stream)
{
    (void)in_sizes; (void)n_in; (void)out_size;
    const float* x     = (const float*)d_in[0];
    const float* h0    = (const float*)d_in[1];
    const float* c0    = (const float*)d_in[2];
    const float* wih_f = (const float*)d_in[3];
    const float* whh_f = (const float*)d_in[4];
    const float* bih_f = (const float*)d_in[5];
    const float* bhh_f = (const float*)d_in[6];
    const float* wih_r = (const float*)d_in[7];
    const float* whh_r = (const float*)d_in[8];
    const float* bih_r = (const float*)d_in[9];
    const float* bhh_r = (const float*)d_in[10];
    float* out = (float*)d_out;

    const size_t gx1 = GX1 * sizeof(bf16);                   // 64 MB per direction
    const size_t needA = 2 * gx1 + 2 * RING_BYTES + 8192;    // ~160 MB
    char* ws = (char*)d_ws;

    if (ws_size >= needA) {
        // Plan A: both directions concurrently (64 4-wave WGs).
        bf16* gx = (bf16*)ws;
        unsigned* ring = (unsigned*)(ws + 2 * gx1);
        unsigned int* bars = (unsigned int*)(ws + 2 * gx1 + 2 * RING_BYTES);
        hipMemsetAsync(bars, 0, 4096, stream);
        dim3 g1(MM / 64, G4 / 128, 2);
        proj_mfma_kernel<<<g1, 256, 0, stream>>>(x, wih_f, wih_r, bih_f, bhh_f, bih_r, bhh_r, gx, 0);
        lstm_rec_kernel<<<dim3(2 * WGD), dim3(256), 0, stream>>>(
            gx, h0, c0, whh_f, whh_r, out, ring, bars, 0);
    } else {
        // Plan B: sequential per-direction, single gx + ring reused (~81 MB).
        bf16* gx = (bf16*)ws;
        unsigned* ring = (unsigned*)(ws + gx1);
        unsigned int* bars = (unsigned int*)(ws + gx1 + RING_BYTES);
        for (int d = 0; d < 2; ++d) {
            hipMemsetAsync(bars, 0, 4096, stream);
            dim3 g1(MM / 64, G4 / 128, 1);
            proj_mfma_kernel<<<g1, 256, 0, stream>>>(x, wih_f, wih_r, bih_f, bhh_f, bih_r, bhh_r, gx, d);
            lstm_rec_kernel<<<dim3(WGD), dim3(256), 0, stream>>>(
                gx, h0, c0, whh_f, whh_r, out, ring, bars, d);
        }
    }
}